// Round 6
// baseline (191.467 us; speedup 1.0000x reference)
//
#include <hip/hip_runtime.h>
#include <math.h>

#define NN 4096
#define DD 256
#define EE 131072
#define MAXD 192
#define SP 196          // padded sS row stride (192%32==0 caused 4-way conflicts)

typedef __attribute__((ext_vector_type(8))) short short8;
typedef __attribute__((ext_vector_type(4))) float float4v;

__device__ __forceinline__ unsigned short f2bf(float f){
    unsigned u = __float_as_uint(f);
    return (unsigned short)((u + 0x7fffu + ((u >> 16) & 1u)) >> 16);   // RNE
}
__device__ __forceinline__ float blo(unsigned u){ return __uint_as_float(u << 16); }
__device__ __forceinline__ float bhi(unsigned u){ return __uint_as_float(u & 0xffff0000u); }

// build one bf16 B-fragment (8 elems) from row-major fp32 weights
__device__ __forceinline__ short8 bfrag(const float* __restrict__ w, int tile, int s, int lane){
    int row = tile * 16 + (lane & 15);
    int k0  = s * 32 + ((lane >> 4) << 3);
    const float* p = w + row * DD + k0;
    short8 v;
    #pragma unroll
    for (int j = 0; j < 8; ++j) v[j] = (short)f2bf(p[j]);
    return v;
}

// ---------------- K1: QKV GEMM (B-fragments from fp32 in-kernel) + fused edge scatter ----------------
__global__ void __launch_bounds__(256) k_gqkv(const float* __restrict__ emb, const float* __restrict__ w,
                                              const float* __restrict__ bias, float* __restrict__ qf,
                                              unsigned short* __restrict__ kb, unsigned short* __restrict__ vb,
                                              const int* __restrict__ ei, unsigned* __restrict__ adj){
    __shared__ float sA[16 * 260];
    int bx = blockIdx.x, by = blockIdx.y;
    int t = threadIdx.x, wv = t >> 6, lane = t & 63;

    // fire-and-forget edge scatter (adj pre-zeroed by memset; completes by kernel end)
    int gid = (by * gridDim.x + bx) * 256 + t;
    if (gid < EE){
        int s = ei[gid], d = ei[EE + gid];
        if (s != d){
            atomicOr(&adj[s * 128 + (d >> 5)], 1u << (d & 31));
            atomicOr(&adj[d * 128 + (s >> 5)], 1u << (s & 31));
        }
    }

    #pragma unroll
    for (int i = 0; i < 16; ++i)
        sA[i * 260 + t] = emb[(bx * 16 + i) * 256 + t];
    __syncthreads();

    int arow = lane & 15, ak0 = (lane >> 4) << 3;
    short8 af[8];
    #pragma unroll
    for (int s = 0; s < 8; ++s){
        const float* p = &sA[arow * 260 + s * 32 + ak0];
        #pragma unroll
        for (int j = 0; j < 8; ++j) af[s][j] = (short)f2bf(p[j]);
    }

    float4v acc[4];
    #pragma unroll
    for (int c = 0; c < 4; ++c) acc[c] = (float4v){0.f, 0.f, 0.f, 0.f};
    #pragma unroll
    for (int s = 0; s < 8; ++s){
        #pragma unroll
        for (int c = 0; c < 4; ++c){
            int to = by * 16 + wv * 4 + c;
            acc[c] = __builtin_amdgcn_mfma_f32_16x16x32_bf16(af[s], bfrag(w, to, s, lane), acc[c], 0, 0, 0);
        }
    }
    int q = lane >> 4, col = lane & 15;
    #pragma unroll
    for (int c = 0; c < 4; ++c){
        int o = (wv * 4 + c) * 16 + col;
        float bo = bias[by * 256 + o];
        #pragma unroll
        for (int r = 0; r < 4; ++r){
            int node = bx * 16 + q * 4 + r;
            float val = acc[c][r] + bo;
            if (by == 0)      qf[node * 256 + o] = val;
            else if (by == 1) kb[node * 256 + o] = f2bf(val);
            else              vb[node * 256 + o] = f2bf(val);
        }
    }
}

// ---------------- K2: attention, one 256-thread block per node; bf16 K/V ----------------
__global__ void __launch_bounds__(256) k_attn(const float* __restrict__ qf, const unsigned short* __restrict__ kb,
                                              const unsigned short* __restrict__ vb, const unsigned* __restrict__ adj,
                                              int* __restrict__ deg, unsigned short* __restrict__ cpk){
    __shared__ float sQ[DD];
    __shared__ float sS[8][SP];
    __shared__ int   sNbr[MAXD];
    __shared__ float sInv[8];
    __shared__ float sV[3 * 64 * 4];
    __shared__ int   sW0, sDeg;
    int n = blockIdx.x, t = threadIdx.x;
    int lane = t & 63;

    sQ[t] = qf[n * 256 + t];

    // --- neighbor extraction (threads 0..127 hold adj words) ---
    unsigned wbits = 0; int c = 0;
    if (t < 128){ wbits = adj[n * 128 + t]; c = __popc(wbits); }
    int pre = c;
    #pragma unroll
    for (int off = 1; off < 64; off <<= 1){
        int tmp = __shfl_up(pre, off);
        if (lane >= off) pre += tmp;
    }
    if (t == 63) sW0 = pre;
    __syncthreads();
    if (t < 128){
        int base = pre - c + ((t >= 64) ? sW0 : 0);
        int mb = t * 32;
        while (wbits){
            int b = __ffs(wbits) - 1; wbits &= wbits - 1u;
            if (base < MAXD) sNbr[base] = mb + b;
            base++;
        }
        if (t == 127){
            int dtot = pre + sW0;
            if (dtot > MAXD) dtot = MAXD;
            sDeg = dtot;
            deg[n] = dtot;
        }
    }
    __syncthreads();
    int dg = sDeg;
    if (dg == 0) return;

    // --- scores: 64 j-slots (j0=t>>2), p=t&3 covers 8 dims/head via one uint4 ---
    int j0 = t >> 2, p = t & 3;
    float4 qp[8][2];
    #pragma unroll
    for (int h = 0; h < 8; ++h){
        qp[h][0] = ((const float4*)sQ)[h * 8 + p * 2];
        qp[h][1] = ((const float4*)sQ)[h * 8 + p * 2 + 1];
    }
    for (int j = j0; j < dg; j += 64){
        const uint4* kr = (const uint4*)(kb + sNbr[j] * 256);
        #pragma unroll
        for (int h = 0; h < 8; ++h){
            uint4 kv = kr[h * 4 + p];
            float s = qp[h][0].x * blo(kv.x) + qp[h][0].y * bhi(kv.x)
                    + qp[h][0].z * blo(kv.y) + qp[h][0].w * bhi(kv.y)
                    + qp[h][1].x * blo(kv.z) + qp[h][1].y * bhi(kv.z)
                    + qp[h][1].z * blo(kv.w) + qp[h][1].w * bhi(kv.w);
            s += __shfl_xor(s, 1); s += __shfl_xor(s, 2);
            if (p == 0) sS[h][j] = s * 0.17677669529663687f;   // 1/sqrt(32)
        }
    }
    __syncthreads();

    // --- softmax per head: 32-lane group h = t>>5 ---
    int h = t >> 5, l = t & 31;
    float m1 = -1e30f;
    for (int j = l; j < dg; j += 32) m1 = fmaxf(m1, sS[h][j]);
    #pragma unroll
    for (int off = 16; off > 0; off >>= 1) m1 = fmaxf(m1, __shfl_xor(m1, off));
    float sum = 0.f;
    for (int j = l; j < dg; j += 32){ float e = __expf(sS[h][j] - m1); sS[h][j] = e; sum += e; }
    #pragma unroll
    for (int off = 16; off > 0; off >>= 1) sum += __shfl_xor(sum, off);
    if (l == 0) sInv[h] = 1.0f / sum;
    __syncthreads();

    // --- values: quad = t>>6 takes j%4; idx = t&63 covers dims 4idx..4idx+3 (8B loads) ---
    int quad = t >> 6, idx = t & 63, h3 = idx >> 3;
    const uint2* vb2 = (const uint2*)vb;
    float4 O = {0.f, 0.f, 0.f, 0.f};
    for (int j = quad; j < dg; j += 4){
        uint2 u = vb2[sNbr[j] * 64 + idx];
        float wgt = sS[h3][j];
        O.x += wgt * blo(u.x); O.y += wgt * bhi(u.x);
        O.z += wgt * blo(u.y); O.w += wgt * bhi(u.y);
    }
    if (quad) ((float4*)sV)[(quad - 1) * 64 + idx] = O;
    __syncthreads();
    if (quad == 0){
        #pragma unroll
        for (int qq = 0; qq < 3; ++qq){
            float4 r = ((float4*)sV)[qq * 64 + idx];
            O.x += r.x; O.y += r.y; O.z += r.z; O.w += r.w;
        }
        float inv = sInv[h3];
        // fused bf16 A-fragment pack of ctx, 8B wide (dims d0..d0+3)
        int d0 = idx * 4;
        int s  = d0 >> 5;
        int l2 = ((d0 >> 3) & 3) * 16 + (n & 15);
        uint2 pk;
        pk.x = (unsigned)f2bf(O.x * inv) | ((unsigned)f2bf(O.y * inv) << 16);
        pk.y = (unsigned)f2bf(O.z * inv) | ((unsigned)f2bf(O.w * inv) << 16);
        ((uint2*)cpk)[(((n >> 4) * 8 + s) * 64 + l2) * 2 + ((d0 & 7) >> 2)] = pk;
    }
}

// ---------------- K3: out-proj + passthrough -> (LDS pack) -> lin -> LayerNorm -> GELU ----------------
__global__ void __launch_bounds__(256) k_tail(const unsigned short* __restrict__ Ap, const float* __restrict__ ow,
                                              const float* __restrict__ ob, const float* __restrict__ emb,
                                              const int* __restrict__ deg, const float* __restrict__ lw,
                                              const float* __restrict__ lb, const float* __restrict__ g,
                                              const float* __restrict__ beta, float* __restrict__ out){
    __shared__ float xs[16 * 264];
    __shared__ short8 sPk[512];
    __shared__ float stat[16][2];
    int bx = blockIdx.x, t = threadIdx.x;
    int wv = t >> 6, lane = t & 63;
    const short8* A8 = (const short8*)Ap;

    float4v acc[4];
    #pragma unroll
    for (int c = 0; c < 4; ++c) acc[c] = (float4v){0.f, 0.f, 0.f, 0.f};
    #pragma unroll
    for (int s = 0; s < 8; ++s){
        short8 a = A8[(bx * 8 + s) * 64 + lane];
        #pragma unroll
        for (int c = 0; c < 4; ++c)
            acc[c] = __builtin_amdgcn_mfma_f32_16x16x32_bf16(a, bfrag(ow, wv * 4 + c, s, lane), acc[c], 0, 0, 0);
    }
    int q = lane >> 4, col = lane & 15;
    #pragma unroll
    for (int c = 0; c < 4; ++c){
        int o = (wv * 4 + c) * 16 + col;
        float bo = ob[o];
        #pragma unroll
        for (int r = 0; r < 4; ++r){
            int row = q * 4 + r, node = bx * 16 + row;
            float x = acc[c][r] + bo;
            if (deg[node] == 0) x = emb[node * 256 + o];
            xs[row * 264 + o] = x;
        }
    }
    __syncthreads();

    // pack x -> bf16 fragments in LDS
    #pragma unroll
    for (int pp = 0; pp < 2; ++pp){
        int e = t + pp * 256;
        int l2 = e & 63, s = e >> 6;
        int m = l2 & 15, k0 = s * 32 + ((l2 >> 4) << 3);
        short8 v;
        #pragma unroll
        for (int j = 0; j < 8; ++j) v[j] = (short)f2bf(xs[m * 264 + k0 + j]);
        sPk[e] = v;
    }
    __syncthreads();

    // lin MFMA
    float4v acc2[4];
    #pragma unroll
    for (int c = 0; c < 4; ++c) acc2[c] = (float4v){0.f, 0.f, 0.f, 0.f};
    #pragma unroll
    for (int s = 0; s < 8; ++s){
        short8 a = sPk[s * 64 + lane];
        #pragma unroll
        for (int c = 0; c < 4; ++c)
            acc2[c] = __builtin_amdgcn_mfma_f32_16x16x32_bf16(a, bfrag(lw, wv * 4 + c, s, lane), acc2[c], 0, 0, 0);
    }
    __syncthreads();                 // xs reads done; reuse as ys
    #pragma unroll
    for (int c = 0; c < 4; ++c){
        int o = (wv * 4 + c) * 16 + col;
        float bo = lb[o];
        #pragma unroll
        for (int r = 0; r < 4; ++r)
            xs[(q * 4 + r) * 264 + o] = acc2[c][r] + bo;
    }
    __syncthreads();

    // LayerNorm + exact GELU
    int rr = t >> 4, i = t & 15;
    float s1 = 0.f, s2 = 0.f;
    #pragma unroll
    for (int jj = 0; jj < 16; ++jj){ float v = xs[rr * 264 + i + 16 * jj]; s1 += v; s2 += v * v; }
    #pragma unroll
    for (int off = 8; off > 0; off >>= 1){ s1 += __shfl_xor(s1, off); s2 += __shfl_xor(s2, off); }
    if (i == 0){
        float mu = s1 * (1.0f / 256.0f);
        float var = s2 * (1.0f / 256.0f) - mu * mu;
        stat[rr][0] = mu;
        stat[rr][1] = rsqrtf(fmaxf(var, 0.f) + 1e-5f);
    }
    __syncthreads();
    float mu = stat[rr][0], rs = stat[rr][1];
    int nbase = (bx * 16 + rr) * 256;
    #pragma unroll
    for (int jj = 0; jj < 16; ++jj){
        int cc = i + 16 * jj;
        float z = (xs[rr * 264 + cc] - mu) * rs * g[cc] + beta[cc];
        out[nbase + cc] = 0.5f * z * (1.0f + erff(z * 0.70710678118654752f));
    }
}

extern "C" void kernel_launch(void* const* d_in, const int* in_sizes, int n_in,
                              void* d_out, int out_size, void* d_ws, size_t ws_size,
                              hipStream_t stream){
    const float* emb = (const float*)d_in[0];
    const int*   ei  = (const int*)d_in[1];
    const float* ipw = (const float*)d_in[2];
    const float* ipb = (const float*)d_in[3];
    const float* ow  = (const float*)d_in[4];
    const float* ob  = (const float*)d_in[5];
    const float* lw  = (const float*)d_in[6];
    const float* lb  = (const float*)d_in[7];
    const float* g   = (const float*)d_in[8];
    const float* bet = (const float*)d_in[9];

    char* ws = (char*)d_ws;
    unsigned*       adj  = (unsigned*)(ws);                    // 2 MiB
    int*            deg  = (int*)(ws + 2097152);               // 16 KiB
    float*          qf   = (float*)(ws + 2113536);             // 4 MiB
    unsigned short* kb   = (unsigned short*)(ws + 6307840);    // 2 MiB
    unsigned short* vb   = (unsigned short*)(ws + 8404992);    // 2 MiB
    unsigned short* cpk  = (unsigned short*)(ws + 10502144);   // 2 MiB

    hipMemsetAsync(adj, 0, 2097152, stream);
    k_gqkv<<<dim3(256, 3), 256, 0, stream>>>(emb, ipw, ipb, qf, kb, vb, ei, adj);
    k_attn<<<NN, 256, 0, stream>>>(qf, kb, vb, adj, deg, cpk);
    k_tail<<<256, 256, 0, stream>>>(cpk, ow, ob, emb, deg, lw, lb, g, bet, (float*)d_out);
}

// Round 7
// 136.220 us; speedup vs baseline: 1.4056x; 1.4056x over previous
//
#include <hip/hip_runtime.h>
#include <math.h>

#define NN 4096
#define DD 256
#define EE 131072
#define MAXD 128
#define SP 132          // sS row stride; 132%32==4 -> conflict-free access patterns

typedef __attribute__((ext_vector_type(8))) short short8;
typedef __attribute__((ext_vector_type(4))) float float4v;

__device__ __forceinline__ unsigned short f2bf(float f){
    unsigned u = __float_as_uint(f);
    return (unsigned short)((u + 0x7fffu + ((u >> 16) & 1u)) >> 16);   // RNE
}
__device__ __forceinline__ float blo(unsigned u){ return __uint_as_float(u << 16); }
__device__ __forceinline__ float bhi(unsigned u){ return __uint_as_float(u & 0xffff0000u); }

// ---------------- K1: pack weights to MFMA fragments + zero adj ----------------
__device__ __forceinline__ void pack_one(const float* __restrict__ src, unsigned short* __restrict__ dst, int e){
    int lane = e & 63;
    int row = ((e >> 9) << 4) + (lane & 15);
    int k0 = ((e >> 6) & 7) * 32 + ((lane >> 4) << 3);
    const float* p = src + row * DD + k0;
    short8 v;
    #pragma unroll
    for (int j = 0; j < 8; ++j) v[j] = (short)f2bf(p[j]);
    ((short8*)dst)[e] = v;
}

__global__ void k_packw(const float* __restrict__ ipw, const float* __restrict__ ow, const float* __restrict__ lw,
                        unsigned short* __restrict__ bipw, unsigned short* __restrict__ bow,
                        unsigned short* __restrict__ blw, unsigned* __restrict__ adj){
    int e = blockIdx.x * 256 + threadIdx.x;       // 40960 threads
    for (int i = e; i < 524288; i += 40960) adj[i] = 0u;   // zero 2MB adj (replaces memset dispatch)
    if (e < 24576)       pack_one(ipw, bipw, e);
    else if (e < 32768)  pack_one(ow,  bow,  e - 24576);
    else                 pack_one(lw,  blw,  e - 32768);
}

// ---------------- K2: scatter edges into bitset (symmetric, no self) ----------------
__global__ void k_edges(const int* __restrict__ ei, unsigned* __restrict__ adj){
    int e = blockIdx.x * 256 + threadIdx.x;
    int s = ei[e];
    int d = ei[EE + e];
    if (s != d){
        atomicOr(&adj[s * 128 + (d >> 5)], 1u << (d & 31));
        atomicOr(&adj[d * 128 + (s >> 5)], 1u << (s & 31));
    }
}

// ---------------- K3: QKV GEMM; A built in-kernel from emb; Q fp32, K/V bf16 ----------------
__global__ void __launch_bounds__(256) k_gqkv(const float* __restrict__ emb, const unsigned short* __restrict__ Bp,
                                              const float* __restrict__ bias, float* __restrict__ qf,
                                              unsigned short* __restrict__ kb, unsigned short* __restrict__ vb){
    __shared__ float sA[16 * 260];
    int bx = blockIdx.x, by = blockIdx.y;
    int t = threadIdx.x, w = t >> 6, lane = t & 63;
    #pragma unroll
    for (int i = 0; i < 16; ++i)
        sA[i * 260 + t] = emb[(bx * 16 + i) * 256 + t];
    __syncthreads();

    int arow = lane & 15, ak0 = (lane >> 4) << 3;
    short8 af[8];
    #pragma unroll
    for (int s = 0; s < 8; ++s){
        const float* p = &sA[arow * 260 + s * 32 + ak0];
        #pragma unroll
        for (int j = 0; j < 8; ++j) af[s][j] = (short)f2bf(p[j]);
    }

    const short8* B8 = (const short8*)Bp;
    float4v acc[4];
    #pragma unroll
    for (int c = 0; c < 4; ++c) acc[c] = (float4v){0.f, 0.f, 0.f, 0.f};
    #pragma unroll
    for (int s = 0; s < 8; ++s){
        #pragma unroll
        for (int c = 0; c < 4; ++c){
            int to = by * 16 + w * 4 + c;
            acc[c] = __builtin_amdgcn_mfma_f32_16x16x32_bf16(af[s], B8[(to * 8 + s) * 64 + lane], acc[c], 0, 0, 0);
        }
    }
    int q = lane >> 4, col = lane & 15;
    #pragma unroll
    for (int c = 0; c < 4; ++c){
        int o = (w * 4 + c) * 16 + col;
        float bo = bias[by * 256 + o];
        #pragma unroll
        for (int r = 0; r < 4; ++r){
            int node = bx * 16 + q * 4 + r;
            float val = acc[c][r] + bo;
            if (by == 0)      qf[node * 256 + o] = val;
            else if (by == 1) kb[node * 256 + o] = f2bf(val);
            else              vb[node * 256 + o] = f2bf(val);
        }
    }
}

// 32-dim bf16 dot against fp32 q fragments (qa[0..7] = head's 32 dims)
__device__ __forceinline__ float dot32(const float4* qa, uint4 a, uint4 b, uint4 c, uint4 d){
    float s;
    s  = qa[0].x*blo(a.x) + qa[0].y*bhi(a.x) + qa[0].z*blo(a.y) + qa[0].w*bhi(a.y);
    s += qa[1].x*blo(a.z) + qa[1].y*bhi(a.z) + qa[1].z*blo(a.w) + qa[1].w*bhi(a.w);
    s += qa[2].x*blo(b.x) + qa[2].y*bhi(b.x) + qa[2].z*blo(b.y) + qa[2].w*bhi(b.y);
    s += qa[3].x*blo(b.z) + qa[3].y*bhi(b.z) + qa[3].z*blo(b.w) + qa[3].w*bhi(b.w);
    s += qa[4].x*blo(c.x) + qa[4].y*bhi(c.x) + qa[4].z*blo(c.y) + qa[4].w*bhi(c.y);
    s += qa[5].x*blo(c.z) + qa[5].y*bhi(c.z) + qa[5].z*blo(c.w) + qa[5].w*bhi(c.w);
    s += qa[6].x*blo(d.x) + qa[6].y*bhi(d.x) + qa[6].z*blo(d.y) + qa[6].w*bhi(d.y);
    s += qa[7].x*blo(d.z) + qa[7].y*bhi(d.z) + qa[7].z*blo(d.w) + qa[7].w*bhi(d.w);
    return s;
}

// ---------------- K4: attention, ONE WAVE PER NODE (no barriers) ----------------
__global__ void __launch_bounds__(128) k_attn(const float* __restrict__ qf, const unsigned short* __restrict__ kb,
                                              const unsigned short* __restrict__ vb, const unsigned* __restrict__ adj,
                                              int* __restrict__ deg, unsigned short* __restrict__ cpk){
    __shared__ int   sNbr[2][MAXD];
    __shared__ float sS[2][8][SP];
    __shared__ float sInv[2][8];
    int wv = threadIdx.x >> 6, lane = threadIdx.x & 63;
    int n = blockIdx.x * 2 + wv;

    // --- neighbor extraction: lane holds adj words 2*lane, 2*lane+1 ---
    uint2 aw = ((const uint2*)(adj + n * 128))[lane];
    int cnt = __popc(aw.x) + __popc(aw.y);
    int pre = cnt;
    #pragma unroll
    for (int off = 1; off < 64; off <<= 1){
        int tmp = __shfl_up(pre, off);
        if (lane >= off) pre += tmp;
    }
    int tot = __shfl(pre, 63);
    int dg = (tot < MAXD) ? tot : MAXD;
    if (lane == 63) deg[n] = dg;
    int base = pre - cnt;
    int mb = lane * 64;
    unsigned b0 = aw.x, b1 = aw.y;
    while (b0){ int b = __ffs(b0) - 1; b0 &= b0 - 1u; if (base < MAXD) sNbr[wv][base] = mb + b; base++; }
    mb += 32;
    while (b1){ int b = __ffs(b1) - 1; b1 &= b1 - 1u; if (base < MAXD) sNbr[wv][base] = mb + b; base++; }
    if (dg == 0) return;                       // wave-uniform; no barriers anywhere
    asm volatile("s_waitcnt lgkmcnt(0)" ::: "memory");   // sNbr visible within wave

    // --- scores: lane = (j-slot js, head h); full 32-dim dot per lane; unroll 2 ---
    int js = lane >> 3, h = lane & 7;
    float4 qa[8];
    const float4* q4 = (const float4*)(qf + n * 256 + h * 32);
    #pragma unroll
    for (int i = 0; i < 8; ++i) qa[i] = q4[i];
    for (int jb = 0; jb < dg; jb += 16){
        int j0 = jb + js, j1 = jb + 8 + js;
        bool v0 = j0 < dg, v1 = j1 < dg;
        int m0 = v0 ? sNbr[wv][j0] : sNbr[wv][0];
        int m1 = v1 ? sNbr[wv][j1] : sNbr[wv][0];
        const uint4* kr0 = (const uint4*)(kb + m0 * 256) + h * 4;
        const uint4* kr1 = (const uint4*)(kb + m1 * 256) + h * 4;
        uint4 a0 = kr0[0], a1 = kr0[1], a2 = kr0[2], a3 = kr0[3];
        uint4 c0 = kr1[0], c1 = kr1[1], c2 = kr1[2], c3 = kr1[3];
        float s0 = dot32(qa, a0, a1, a2, a3) * 0.17677669529663687f;
        float s1 = dot32(qa, c0, c1, c2, c3) * 0.17677669529663687f;
        if (v0) sS[wv][h][j0] = s0;
        if (v1) sS[wv][h][j1] = s1;
    }
    asm volatile("s_waitcnt lgkmcnt(0)" ::: "memory");

    // --- softmax: lane = (h2 = lane>>3, i2 = lane&7), reduce within 8-lane group ---
    int h2 = lane >> 3, i2 = lane & 7;
    float m1 = -1e30f;
    for (int j = i2; j < dg; j += 8) m1 = fmaxf(m1, sS[wv][h2][j]);
    m1 = fmaxf(m1, __shfl_xor(m1, 1));
    m1 = fmaxf(m1, __shfl_xor(m1, 2));
    m1 = fmaxf(m1, __shfl_xor(m1, 4));
    float sum = 0.f;
    for (int j = i2; j < dg; j += 8){ float e = __expf(sS[wv][h2][j] - m1); sS[wv][h2][j] = e; sum += e; }
    sum += __shfl_xor(sum, 1);
    sum += __shfl_xor(sum, 2);
    sum += __shfl_xor(sum, 4);
    if (i2 == 0) sInv[wv][h2] = 1.0f / sum;
    asm volatile("s_waitcnt lgkmcnt(0)" ::: "memory");

    // --- values: lane covers dims 4*lane..4*lane+3; 4-way j-unroll; 8B loads ---
    int h3 = lane >> 3;                        // head of this lane's dims
    const uint2* vb2 = (const uint2*)vb;
    float4 O = {0.f, 0.f, 0.f, 0.f};
    int j = 0;
    for (; j + 4 <= dg; j += 4){
        int m0 = sNbr[wv][j], m1_ = sNbr[wv][j + 1], m2 = sNbr[wv][j + 2], m3 = sNbr[wv][j + 3];
        uint2 u0 = vb2[m0 * 64 + lane];
        uint2 u1 = vb2[m1_ * 64 + lane];
        uint2 u2 = vb2[m2 * 64 + lane];
        uint2 u3 = vb2[m3 * 64 + lane];
        float w0 = sS[wv][h3][j], w1 = sS[wv][h3][j + 1], w2 = sS[wv][h3][j + 2], w3 = sS[wv][h3][j + 3];
        O.x += w0 * blo(u0.x) + w1 * blo(u1.x) + w2 * blo(u2.x) + w3 * blo(u3.x);
        O.y += w0 * bhi(u0.x) + w1 * bhi(u1.x) + w2 * bhi(u2.x) + w3 * bhi(u3.x);
        O.z += w0 * blo(u0.y) + w1 * blo(u1.y) + w2 * blo(u2.y) + w3 * blo(u3.y);
        O.w += w0 * bhi(u0.y) + w1 * bhi(u1.y) + w2 * bhi(u2.y) + w3 * bhi(u3.y);
    }
    for (; j < dg; ++j){
        uint2 u = vb2[sNbr[wv][j] * 64 + lane];
        float wgt = sS[wv][h3][j];
        O.x += wgt * blo(u.x); O.y += wgt * bhi(u.x);
        O.z += wgt * blo(u.y); O.w += wgt * bhi(u.y);
    }
    float inv = sInv[wv][h3];

    // --- fused bf16 A-fragment pack of ctx (verified index math) ---
    int d0 = lane * 4;
    int s  = d0 >> 5;
    int l2 = ((d0 >> 3) & 3) * 16 + (n & 15);
    uint2 pk;
    pk.x = (unsigned)f2bf(O.x * inv) | ((unsigned)f2bf(O.y * inv) << 16);
    pk.y = (unsigned)f2bf(O.z * inv) | ((unsigned)f2bf(O.w * inv) << 16);
    ((uint2*)cpk)[(((n >> 4) * 8 + s) * 64 + l2) * 2 + ((d0 & 7) >> 2)] = pk;
}

// ---------------- K5: out-proj + passthrough -> (LDS pack) -> lin -> LayerNorm -> GELU ----------------
__global__ void __launch_bounds__(256) k_tail(const unsigned short* __restrict__ Ap, const unsigned short* __restrict__ Bow,
                                              const float* __restrict__ ob, const float* __restrict__ emb,
                                              const int* __restrict__ deg, const unsigned short* __restrict__ Blw,
                                              const float* __restrict__ lb, const float* __restrict__ g,
                                              const float* __restrict__ beta, float* __restrict__ out){
    __shared__ float xs[16 * 264];
    __shared__ short8 sPk[512];
    __shared__ float stat[16][2];
    int bx = blockIdx.x, t = threadIdx.x;
    int w = t >> 6, lane = t & 63;
    const short8* A8 = (const short8*)Ap;
    const short8* B8 = (const short8*)Bow;

    float4v acc[4];
    #pragma unroll
    for (int c = 0; c < 4; ++c) acc[c] = (float4v){0.f, 0.f, 0.f, 0.f};
    #pragma unroll
    for (int s = 0; s < 8; ++s){
        short8 a = A8[(bx * 8 + s) * 64 + lane];
        #pragma unroll
        for (int c = 0; c < 4; ++c)
            acc[c] = __builtin_amdgcn_mfma_f32_16x16x32_bf16(a, B8[((w * 4 + c) * 8 + s) * 64 + lane], acc[c], 0, 0, 0);
    }
    int q = lane >> 4, col = lane & 15;
    #pragma unroll
    for (int c = 0; c < 4; ++c){
        int o = (w * 4 + c) * 16 + col;
        float bo = ob[o];
        #pragma unroll
        for (int r = 0; r < 4; ++r){
            int row = q * 4 + r, node = bx * 16 + row;
            float x = acc[c][r] + bo;
            if (deg[node] == 0) x = emb[node * 256 + o];
            xs[row * 264 + o] = x;
        }
    }
    __syncthreads();

    // pack x -> bf16 fragments in LDS
    #pragma unroll
    for (int pp = 0; pp < 2; ++pp){
        int e = t + pp * 256;
        int l2 = e & 63, s = e >> 6;
        int m = l2 & 15, k0 = s * 32 + ((l2 >> 4) << 3);
        short8 v;
        #pragma unroll
        for (int j = 0; j < 8; ++j) v[j] = (short)f2bf(xs[m * 264 + k0 + j]);
        sPk[e] = v;
    }
    __syncthreads();

    // lin MFMA
    const short8* B2 = (const short8*)Blw;
    float4v acc2[4];
    #pragma unroll
    for (int c = 0; c < 4; ++c) acc2[c] = (float4v){0.f, 0.f, 0.f, 0.f};
    #pragma unroll
    for (int s = 0; s < 8; ++s){
        short8 a = sPk[s * 64 + lane];
        #pragma unroll
        for (int c = 0; c < 4; ++c)
            acc2[c] = __builtin_amdgcn_mfma_f32_16x16x32_bf16(a, B2[((w * 4 + c) * 8 + s) * 64 + lane], acc2[c], 0, 0, 0);
    }
    __syncthreads();                 // xs reads done; reuse as ys
    #pragma unroll
    for (int c = 0; c < 4; ++c){
        int o = (w * 4 + c) * 16 + col;
        float bo = lb[o];
        #pragma unroll
        for (int r = 0; r < 4; ++r)
            xs[(q * 4 + r) * 264 + o] = acc2[c][r] + bo;
    }
    __syncthreads();

    // LayerNorm + exact GELU
    int rr = t >> 4, i = t & 15;
    float s1 = 0.f, s2 = 0.f;
    #pragma unroll
    for (int jj = 0; jj < 16; ++jj){ float v = xs[rr * 264 + i + 16 * jj]; s1 += v; s2 += v * v; }
    #pragma unroll
    for (int off = 8; off > 0; off >>= 1){ s1 += __shfl_xor(s1, off); s2 += __shfl_xor(s2, off); }
    if (i == 0){
        float mu = s1 * (1.0f / 256.0f);
        float var = s2 * (1.0f / 256.0f) - mu * mu;
        stat[rr][0] = mu;
        stat[rr][1] = rsqrtf(fmaxf(var, 0.f) + 1e-5f);
    }
    __syncthreads();
    float mu = stat[rr][0], rs = stat[rr][1];
    int nbase = (bx * 16 + rr) * 256;
    #pragma unroll
    for (int jj = 0; jj < 16; ++jj){
        int cc = i + 16 * jj;
        float z = (xs[rr * 264 + cc] - mu) * rs * g[cc] + beta[cc];
        out[nbase + cc] = 0.5f * z * (1.0f + erff(z * 0.70710678118654752f));
    }
}

extern "C" void kernel_launch(void* const* d_in, const int* in_sizes, int n_in,
                              void* d_out, int out_size, void* d_ws, size_t ws_size,
                              hipStream_t stream){
    const float* emb = (const float*)d_in[0];
    const int*   ei  = (const int*)d_in[1];
    const float* ipw = (const float*)d_in[2];
    const float* ipb = (const float*)d_in[3];
    const float* ow  = (const float*)d_in[4];
    const float* ob  = (const float*)d_in[5];
    const float* lw  = (const float*)d_in[6];
    const float* lb  = (const float*)d_in[7];
    const float* g   = (const float*)d_in[8];
    const float* bet = (const float*)d_in[9];

    char* ws = (char*)d_ws;
    unsigned*       adj  = (unsigned*)(ws);                    // 2 MiB
    int*            deg  = (int*)(ws + 2097152);               // 16 KiB
    unsigned short* bipw = (unsigned short*)(ws + 2113536);    // 384 KiB
    unsigned short* bow  = (unsigned short*)(ws + 2506752);    // 128 KiB
    unsigned short* blw  = (unsigned short*)(ws + 2637824);    // 128 KiB
    float*          qf   = (float*)(ws + 2768896);             // 4 MiB
    unsigned short* kb   = (unsigned short*)(ws + 6963200);    // 2 MiB
    unsigned short* vb   = (unsigned short*)(ws + 9060352);    // 2 MiB
    unsigned short* cpk  = (unsigned short*)(ws + 11157504);   // 2 MiB

    k_packw<<<160, 256, 0, stream>>>(ipw, ow, lw, bipw, bow, blw, adj);
    k_edges<<<EE / 256, 256, 0, stream>>>(ei, adj);
    k_gqkv <<<dim3(256, 3), 256, 0, stream>>>(emb, bipw, ipb, qf, kb, vb);
    k_attn <<<NN / 2, 128, 0, stream>>>(qf, kb, vb, adj, deg, cpk);
    k_tail <<<256, 256, 0, stream>>>(cpk, bow, ob, emb, deg, blw, lb, g, bet, (float*)d_out);
}

// Round 8
// 129.739 us; speedup vs baseline: 1.4758x; 1.0500x over previous
//
#include <hip/hip_runtime.h>
#include <math.h>

#define NN 4096
#define DD 256
#define EE 131072
#define MAXD 128
#define SP 132          // sS row stride; 132%32==4 -> conflict-free

typedef __attribute__((ext_vector_type(8))) short short8;
typedef __attribute__((ext_vector_type(4))) float float4v;

__device__ __forceinline__ unsigned short f2bf(float f){
    unsigned u = __float_as_uint(f);
    return (unsigned short)((u + 0x7fffu + ((u >> 16) & 1u)) >> 16);   // RNE
}
__device__ __forceinline__ float blo(unsigned u){ return __uint_as_float(u << 16); }
__device__ __forceinline__ float bhi(unsigned u){ return __uint_as_float(u & 0xffff0000u); }

// ---------------- K1: pack weights to MFMA fragments + zero adj ----------------
__device__ __forceinline__ void pack_one(const float* __restrict__ src, unsigned short* __restrict__ dst, int e){
    int lane = e & 63;
    int row = ((e >> 9) << 4) + (lane & 15);
    int k0 = ((e >> 6) & 7) * 32 + ((lane >> 4) << 3);
    const float* p = src + row * DD + k0;
    short8 v;
    #pragma unroll
    for (int j = 0; j < 8; ++j) v[j] = (short)f2bf(p[j]);
    ((short8*)dst)[e] = v;
}

__global__ void k_packw(const float* __restrict__ ipw, const float* __restrict__ ow, const float* __restrict__ lw,
                        unsigned short* __restrict__ bipw, unsigned short* __restrict__ bow,
                        unsigned short* __restrict__ blw, unsigned* __restrict__ adj){
    int e = blockIdx.x * 256 + threadIdx.x;       // 40960 threads
    for (int i = e; i < 524288; i += 40960) adj[i] = 0u;   // zero 2MB adj
    if (e < 24576)       pack_one(ipw, bipw, e);
    else if (e < 32768)  pack_one(ow,  bow,  e - 24576);
    else                 pack_one(lw,  blw,  e - 32768);
}

// ---------------- K2: QKV GEMM (Q fp32, K/V bf16) + fused edge scatter ----------------
__global__ void __launch_bounds__(256) k_gqkv(const float* __restrict__ emb, const unsigned short* __restrict__ Bp,
                                              const float* __restrict__ bias, float* __restrict__ qf,
                                              unsigned short* __restrict__ kb, unsigned short* __restrict__ vb,
                                              const int* __restrict__ ei, unsigned* __restrict__ adj){
    __shared__ float sA[16 * 260];
    int bx = blockIdx.x, by = blockIdx.y;
    int t = threadIdx.x, w = t >> 6, lane = t & 63;

    // fire-and-forget edge scatter (adj zeroed by k_packw; visible to next dispatch)
    int gid = (by * gridDim.x + bx) * 256 + t;    // 196608 threads for 131072 edges
    if (gid < EE){
        int s = ei[gid], d = ei[EE + gid];
        if (s != d){
            atomicOr(&adj[s * 128 + (d >> 5)], 1u << (d & 31));
            atomicOr(&adj[d * 128 + (s >> 5)], 1u << (s & 31));
        }
    }

    #pragma unroll
    for (int i = 0; i < 16; ++i)
        sA[i * 260 + t] = emb[(bx * 16 + i) * 256 + t];
    __syncthreads();

    int arow = lane & 15, ak0 = (lane >> 4) << 3;
    short8 af[8];
    #pragma unroll
    for (int s = 0; s < 8; ++s){
        const float* p = &sA[arow * 260 + s * 32 + ak0];
        #pragma unroll
        for (int j = 0; j < 8; ++j) af[s][j] = (short)f2bf(p[j]);
    }

    const short8* B8 = (const short8*)Bp;
    float4v acc[4];
    #pragma unroll
    for (int c = 0; c < 4; ++c) acc[c] = (float4v){0.f, 0.f, 0.f, 0.f};
    #pragma unroll
    for (int s = 0; s < 8; ++s){
        #pragma unroll
        for (int c = 0; c < 4; ++c){
            int to = by * 16 + w * 4 + c;
            acc[c] = __builtin_amdgcn_mfma_f32_16x16x32_bf16(af[s], B8[(to * 8 + s) * 64 + lane], acc[c], 0, 0, 0);
        }
    }
    int q = lane >> 4, col = lane & 15;
    #pragma unroll
    for (int c = 0; c < 4; ++c){
        int o = (w * 4 + c) * 16 + col;
        float bo = bias[by * 256 + o];
        #pragma unroll
        for (int r = 0; r < 4; ++r){
            int node = bx * 16 + q * 4 + r;
            float val = acc[c][r] + bo;
            if (by == 0)      qf[node * 256 + o] = val;
            else if (by == 1) kb[node * 256 + o] = f2bf(val);
            else              vb[node * 256 + o] = f2bf(val);
        }
    }
}

// 32-dim bf16 dot against fp32 q fragments
__device__ __forceinline__ float dot32(const float4* qa, uint4 a, uint4 b, uint4 c, uint4 d){
    float s;
    s  = qa[0].x*blo(a.x) + qa[0].y*bhi(a.x) + qa[0].z*blo(a.y) + qa[0].w*bhi(a.y);
    s += qa[1].x*blo(a.z) + qa[1].y*bhi(a.z) + qa[1].z*blo(a.w) + qa[1].w*bhi(a.w);
    s += qa[2].x*blo(b.x) + qa[2].y*bhi(b.x) + qa[2].z*blo(b.y) + qa[2].w*bhi(b.y);
    s += qa[3].x*blo(b.z) + qa[3].y*bhi(b.z) + qa[3].z*blo(b.w) + qa[3].w*bhi(b.w);
    s += qa[4].x*blo(c.x) + qa[4].y*bhi(c.x) + qa[4].z*blo(c.y) + qa[4].w*bhi(c.y);
    s += qa[5].x*blo(c.z) + qa[5].y*bhi(c.z) + qa[5].z*blo(c.w) + qa[5].w*bhi(c.w);
    s += qa[6].x*blo(d.x) + qa[6].y*bhi(d.x) + qa[6].z*blo(d.y) + qa[6].w*bhi(d.y);
    s += qa[7].x*blo(d.z) + qa[7].y*bhi(d.z) + qa[7].z*blo(d.w) + qa[7].w*bhi(d.w);
    return s;
}

// ---------------- K3: fused attention + tail. 512 threads = 8 waves x 2 nodes = 16-node tile ----
__global__ void __launch_bounds__(512) k_attn_tail(
        const float* __restrict__ qf, const unsigned short* __restrict__ kb,
        const unsigned short* __restrict__ vb, const unsigned* __restrict__ adj,
        const float* __restrict__ emb,
        const unsigned short* __restrict__ Bow, const float* __restrict__ ob,
        const unsigned short* __restrict__ Blw, const float* __restrict__ lb,
        const float* __restrict__ g, const float* __restrict__ beta,
        float* __restrict__ out){
    __shared__ float  sS[8][8][SP];      // 33.8 KB; later reused as xs[16*264]
    __shared__ int    sNbr[8][MAXD];     // 4 KB
    __shared__ short8 sPk[512];          // 8 KB ctx/x fragments
    __shared__ float  sInv[8][8];
    __shared__ int    sDeg[16];
    __shared__ float  stat[16][2];
    int bx = blockIdx.x, t = threadIdx.x;
    int wv = t >> 6, lane = t & 63;
    int n0 = bx * 16;
    float* xs = (float*)sS;              // 16*264 = 4224 floats fits in sS (4224*2)

    // ======== ATTENTION: wave wv handles nodes n0 + wv*2 + {0,1}, no barriers ========
    for (int u = 0; u < 2; ++u){
        int m = wv * 2 + u;              // row within tile = n & 15
        int n = n0 + m;

        // --- neighbor extraction: lane holds adj words 2*lane, 2*lane+1 ---
        uint2 aw = ((const uint2*)(adj + n * 128))[lane];
        int cnt = __popc(aw.x) + __popc(aw.y);
        int pre = cnt;
        #pragma unroll
        for (int off = 1; off < 64; off <<= 1){
            int tmp = __shfl_up(pre, off);
            if (lane >= off) pre += tmp;
        }
        int tot = __shfl(pre, 63);
        int dg = (tot < MAXD) ? tot : MAXD;
        if (lane == 63) sDeg[m] = dg;
        int base = pre - cnt;
        int mb = lane * 64;
        unsigned b0 = aw.x, b1 = aw.y;
        while (b0){ int b = __ffs(b0) - 1; b0 &= b0 - 1u; if (base < MAXD) sNbr[wv][base] = mb + b; base++; }
        mb += 32;
        while (b1){ int b = __ffs(b1) - 1; b1 &= b1 - 1u; if (base < MAXD) sNbr[wv][base] = mb + b; base++; }
        if (dg == 0) continue;           // wave-uniform; sPk row left garbage (overridden by passthrough)
        asm volatile("s_waitcnt lgkmcnt(0)" ::: "memory");

        // --- scores: lane = (j-slot js = lane>>3, head h = lane&7); 2-way j unroll ---
        int js = lane >> 3, h = lane & 7;
        float4 qa[8];
        const float4* q4 = (const float4*)(qf + n * 256 + h * 32);
        #pragma unroll
        for (int i = 0; i < 8; ++i) qa[i] = q4[i];
        for (int jb = 0; jb < dg; jb += 16){
            int j0 = jb + js, j1 = jb + 8 + js;
            bool v0 = j0 < dg, v1 = j1 < dg;
            int m0 = v0 ? sNbr[wv][j0] : sNbr[wv][0];
            int m1 = v1 ? sNbr[wv][j1] : sNbr[wv][0];
            const uint4* kr0 = (const uint4*)(kb + m0 * 256) + h * 4;
            const uint4* kr1 = (const uint4*)(kb + m1 * 256) + h * 4;
            uint4 a0 = kr0[0], a1 = kr0[1], a2 = kr0[2], a3 = kr0[3];
            uint4 c0 = kr1[0], c1 = kr1[1], c2 = kr1[2], c3 = kr1[3];
            float s0 = dot32(qa, a0, a1, a2, a3) * 0.17677669529663687f;
            float s1 = dot32(qa, c0, c1, c2, c3) * 0.17677669529663687f;
            if (v0) sS[wv][h][j0] = s0;
            if (v1) sS[wv][h][j1] = s1;
        }
        asm volatile("s_waitcnt lgkmcnt(0)" ::: "memory");

        // --- softmax: lane = (h2 = lane>>3, i2 = lane&7) ---
        int h2 = lane >> 3, i2 = lane & 7;
        float m1 = -1e30f;
        for (int j = i2; j < dg; j += 8) m1 = fmaxf(m1, sS[wv][h2][j]);
        m1 = fmaxf(m1, __shfl_xor(m1, 1));
        m1 = fmaxf(m1, __shfl_xor(m1, 2));
        m1 = fmaxf(m1, __shfl_xor(m1, 4));
        float sum = 0.f;
        for (int j = i2; j < dg; j += 8){ float e = __expf(sS[wv][h2][j] - m1); sS[wv][h2][j] = e; sum += e; }
        sum += __shfl_xor(sum, 1);
        sum += __shfl_xor(sum, 2);
        sum += __shfl_xor(sum, 4);
        if (i2 == 0) sInv[wv][h2] = 1.0f / sum;
        asm volatile("s_waitcnt lgkmcnt(0)" ::: "memory");

        // --- values: lane covers dims 4*lane..4*lane+3; 8-way j unroll; 8B loads ---
        int h3 = lane >> 3;
        const uint2* vb2 = (const uint2*)vb;
        float4 O = {0.f, 0.f, 0.f, 0.f};
        int j = 0;
        for (; j + 8 <= dg; j += 8){
            uint2 uu[8]; float ww[8];
            #pragma unroll
            for (int k = 0; k < 8; ++k){
                uu[k] = vb2[sNbr[wv][j + k] * 64 + lane];
                ww[k] = sS[wv][h3][j + k];
            }
            #pragma unroll
            for (int k = 0; k < 8; ++k){
                O.x += ww[k] * blo(uu[k].x); O.y += ww[k] * bhi(uu[k].x);
                O.z += ww[k] * blo(uu[k].y); O.w += ww[k] * bhi(uu[k].y);
            }
        }
        for (; j < dg; ++j){
            uint2 u = vb2[sNbr[wv][j] * 64 + lane];
            float wgt = sS[wv][h3][j];
            O.x += wgt * blo(u.x); O.y += wgt * bhi(u.x);
            O.z += wgt * blo(u.y); O.w += wgt * bhi(u.y);
        }
        float inv = sInv[wv][h3];

        // --- pack ctx row m into LDS A-fragments ---
        int d0 = lane * 4;
        int s  = d0 >> 5;
        int l2 = ((d0 >> 3) & 3) * 16 + m;
        uint2 pk;
        pk.x = (unsigned)f2bf(O.x * inv) | ((unsigned)f2bf(O.y * inv) << 16);
        pk.y = (unsigned)f2bf(O.z * inv) | ((unsigned)f2bf(O.w * inv) << 16);
        ((uint2*)sPk)[(s * 64 + l2) * 2 + ((d0 & 7) >> 2)] = pk;
    }
    __syncthreads();

    // ======== TAIL: out-proj + passthrough -> pack -> lin -> LayerNorm -> GELU ========
    // 8 waves x 2 col-tiles each = 256 output cols
    const short8* B8 = (const short8*)Bow;
    float4v acc[2];
    #pragma unroll
    for (int c = 0; c < 2; ++c) acc[c] = (float4v){0.f, 0.f, 0.f, 0.f};
    #pragma unroll
    for (int s = 0; s < 8; ++s){
        short8 a = sPk[s * 64 + lane];
        #pragma unroll
        for (int c = 0; c < 2; ++c)
            acc[c] = __builtin_amdgcn_mfma_f32_16x16x32_bf16(a, B8[((wv * 2 + c) * 8 + s) * 64 + lane], acc[c], 0, 0, 0);
    }
    int q = lane >> 4, col = lane & 15;
    #pragma unroll
    for (int c = 0; c < 2; ++c){
        int o = (wv * 2 + c) * 16 + col;
        float bo = ob[o];
        #pragma unroll
        for (int r = 0; r < 4; ++r){
            int row = q * 4 + r;
            float x = acc[c][r] + bo;
            if (sDeg[row] == 0) x = emb[(n0 + row) * 256 + o];
            xs[row * 264 + o] = x;
        }
    }
    __syncthreads();

    // pack x -> bf16 fragments in LDS (512 entries, one per thread)
    {
        int l2 = t & 63, s = t >> 6;
        int m = l2 & 15, k0 = s * 32 + ((l2 >> 4) << 3);
        short8 v;
        #pragma unroll
        for (int j = 0; j < 8; ++j) v[j] = (short)f2bf(xs[m * 264 + k0 + j]);
        __syncthreads();                 // all xs reads... ensure pack reads done before sPk overwrite
        sPk[t] = v;
    }
    __syncthreads();

    // lin MFMA
    const short8* B2 = (const short8*)Blw;
    float4v acc2[2];
    #pragma unroll
    for (int c = 0; c < 2; ++c) acc2[c] = (float4v){0.f, 0.f, 0.f, 0.f};
    #pragma unroll
    for (int s = 0; s < 8; ++s){
        short8 a = sPk[s * 64 + lane];
        #pragma unroll
        for (int c = 0; c < 2; ++c)
            acc2[c] = __builtin_amdgcn_mfma_f32_16x16x32_bf16(a, B2[((wv * 2 + c) * 8 + s) * 64 + lane], acc2[c], 0, 0, 0);
    }
    __syncthreads();                     // xs reads done; reuse as ys
    #pragma unroll
    for (int c = 0; c < 2; ++c){
        int o = (wv * 2 + c) * 16 + col;
        float bo = lb[o];
        #pragma unroll
        for (int r = 0; r < 4; ++r)
            xs[(q * 4 + r) * 264 + o] = acc2[c][r] + bo;
    }
    __syncthreads();

    // LayerNorm + exact GELU: rr = t>>5 (16 rows), i = t&31 (8 cols each)
    int rr = t >> 5, i = t & 31;
    float s1 = 0.f, s2 = 0.f;
    #pragma unroll
    for (int jj = 0; jj < 8; ++jj){ float v = xs[rr * 264 + i + 32 * jj]; s1 += v; s2 += v * v; }
    #pragma unroll
    for (int off = 16; off > 0; off >>= 1){ s1 += __shfl_xor(s1, off); s2 += __shfl_xor(s2, off); }
    if (i == 0){
        float mu = s1 * (1.0f / 256.0f);
        float var = s2 * (1.0f / 256.0f) - mu * mu;
        stat[rr][0] = mu;
        stat[rr][1] = rsqrtf(fmaxf(var, 0.f) + 1e-5f);
    }
    __syncthreads();
    float mu = stat[rr][0], rs = stat[rr][1];
    int nbase = (n0 + rr) * 256;
    #pragma unroll
    for (int jj = 0; jj < 8; ++jj){
        int cc = i + 32 * jj;
        float z = (xs[rr * 264 + cc] - mu) * rs * g[cc] + beta[cc];
        out[nbase + cc] = 0.5f * z * (1.0f + erff(z * 0.70710678118654752f));
    }
}

extern "C" void kernel_launch(void* const* d_in, const int* in_sizes, int n_in,
                              void* d_out, int out_size, void* d_ws, size_t ws_size,
                              hipStream_t stream){
    const float* emb = (const float*)d_in[0];
    const int*   ei  = (const int*)d_in[1];
    const float* ipw = (const float*)d_in[2];
    const float* ipb = (const float*)d_in[3];
    const float* ow  = (const float*)d_in[4];
    const float* ob  = (const float*)d_in[5];
    const float* lw  = (const float*)d_in[6];
    const float* lb  = (const float*)d_in[7];
    const float* g   = (const float*)d_in[8];
    const float* bet = (const float*)d_in[9];

    char* ws = (char*)d_ws;
    unsigned*       adj  = (unsigned*)(ws);                    // 2 MiB
    unsigned short* bipw = (unsigned short*)(ws + 2113536);    // 384 KiB
    unsigned short* bow  = (unsigned short*)(ws + 2506752);    // 128 KiB
    unsigned short* blw  = (unsigned short*)(ws + 2637824);    // 128 KiB
    float*          qf   = (float*)(ws + 2768896);             // 4 MiB
    unsigned short* kb   = (unsigned short*)(ws + 6963200);    // 2 MiB
    unsigned short* vb   = (unsigned short*)(ws + 9060352);    // 2 MiB

    k_packw    <<<160, 256, 0, stream>>>(ipw, ow, lw, bipw, bow, blw, adj);
    k_gqkv     <<<dim3(256, 3), 256, 0, stream>>>(emb, bipw, ipb, qf, kb, vb, ei, adj);
    k_attn_tail<<<256, 512, 0, stream>>>(qf, kb, vb, adj, emb, bow, ob, blw, lb, g, bet, (float*)d_out);
}

// Round 9
// 125.063 us; speedup vs baseline: 1.5310x; 1.0374x over previous
//
#include <hip/hip_runtime.h>
#include <math.h>

#define NN 4096
#define DD 256
#define EE 131072
#define MAXD 128
#define SP 132          // sS row stride; 132%32==4 -> conflict-free

typedef __attribute__((ext_vector_type(8))) short short8;
typedef __attribute__((ext_vector_type(4))) float float4v;

__device__ __forceinline__ unsigned short f2bf(float f){
    unsigned u = __float_as_uint(f);
    return (unsigned short)((u + 0x7fffu + ((u >> 16) & 1u)) >> 16);   // RNE
}
__device__ __forceinline__ float blo(unsigned u){ return __uint_as_float(u << 16); }
__device__ __forceinline__ float bhi(unsigned u){ return __uint_as_float(u & 0xffff0000u); }

// ---------------- K1: pack weights to MFMA fragments + zero adj ----------------
__device__ __forceinline__ void pack_one(const float* __restrict__ src, unsigned short* __restrict__ dst, int e){
    int lane = e & 63;
    int row = ((e >> 9) << 4) + (lane & 15);
    int k0 = ((e >> 6) & 7) * 32 + ((lane >> 4) << 3);
    const float* p = src + row * DD + k0;
    short8 v;
    #pragma unroll
    for (int j = 0; j < 8; ++j) v[j] = (short)f2bf(p[j]);
    ((short8*)dst)[e] = v;
}

__global__ void k_packw(const float* __restrict__ ipw, const float* __restrict__ ow, const float* __restrict__ lw,
                        unsigned short* __restrict__ bipw, unsigned short* __restrict__ bow,
                        unsigned short* __restrict__ blw, unsigned* __restrict__ adj){
    int e = blockIdx.x * 256 + threadIdx.x;       // 40960 threads
    for (int i = e; i < 524288; i += 40960) adj[i] = 0u;   // zero 2MB adj
    if (e < 24576)       pack_one(ipw, bipw, e);
    else if (e < 32768)  pack_one(ow,  bow,  e - 24576);
    else                 pack_one(lw,  blw,  e - 32768);
}

// ---------------- K2: QKV GEMM (Q fp32, K/V bf16) + fused edge scatter ----------------
__global__ void __launch_bounds__(256) k_gqkv(const float* __restrict__ emb, const unsigned short* __restrict__ Bp,
                                              const float* __restrict__ bias, float* __restrict__ qf,
                                              unsigned short* __restrict__ kb, unsigned short* __restrict__ vb,
                                              const int* __restrict__ ei, unsigned* __restrict__ adj){
    __shared__ float sA[16 * 260];
    int bx = blockIdx.x, by = blockIdx.y;
    int t = threadIdx.x, w = t >> 6, lane = t & 63;

    // fire-and-forget edge scatter (adj zeroed by k_packw)
    int gid = (by * gridDim.x + bx) * 256 + t;
    if (gid < EE){
        int s = ei[gid], d = ei[EE + gid];
        if (s != d){
            atomicOr(&adj[s * 128 + (d >> 5)], 1u << (d & 31));
            atomicOr(&adj[d * 128 + (s >> 5)], 1u << (s & 31));
        }
    }

    #pragma unroll
    for (int i = 0; i < 16; ++i)
        sA[i * 260 + t] = emb[(bx * 16 + i) * 256 + t];
    __syncthreads();

    int arow = lane & 15, ak0 = (lane >> 4) << 3;
    short8 af[8];
    #pragma unroll
    for (int s = 0; s < 8; ++s){
        const float* p = &sA[arow * 260 + s * 32 + ak0];
        #pragma unroll
        for (int j = 0; j < 8; ++j) af[s][j] = (short)f2bf(p[j]);
    }

    const short8* B8 = (const short8*)Bp;
    float4v acc[4];
    #pragma unroll
    for (int c = 0; c < 4; ++c) acc[c] = (float4v){0.f, 0.f, 0.f, 0.f};
    #pragma unroll
    for (int s = 0; s < 8; ++s){
        #pragma unroll
        for (int c = 0; c < 4; ++c){
            int to = by * 16 + w * 4 + c;
            acc[c] = __builtin_amdgcn_mfma_f32_16x16x32_bf16(af[s], B8[(to * 8 + s) * 64 + lane], acc[c], 0, 0, 0);
        }
    }
    int q = lane >> 4, col = lane & 15;
    #pragma unroll
    for (int c = 0; c < 4; ++c){
        int o = (w * 4 + c) * 16 + col;
        float bo = bias[by * 256 + o];
        #pragma unroll
        for (int r = 0; r < 4; ++r){
            int node = bx * 16 + q * 4 + r;
            float val = acc[c][r] + bo;
            if (by == 0)      qf[node * 256 + o] = val;
            else if (by == 1) kb[node * 256 + o] = f2bf(val);
            else              vb[node * 256 + o] = f2bf(val);
        }
    }
}

// 32-dim bf16 dot against fp32 q fragments
__device__ __forceinline__ float dot32(const float4* qa, uint4 a, uint4 b, uint4 c, uint4 d){
    float s;
    s  = qa[0].x*blo(a.x) + qa[0].y*bhi(a.x) + qa[0].z*blo(a.y) + qa[0].w*bhi(a.y);
    s += qa[1].x*blo(a.z) + qa[1].y*bhi(a.z) + qa[1].z*blo(a.w) + qa[1].w*bhi(a.w);
    s += qa[2].x*blo(b.x) + qa[2].y*bhi(b.x) + qa[2].z*blo(b.y) + qa[2].w*bhi(b.y);
    s += qa[3].x*blo(b.z) + qa[3].y*bhi(b.z) + qa[3].z*blo(b.w) + qa[3].w*bhi(b.w);
    s += qa[4].x*blo(c.x) + qa[4].y*bhi(c.x) + qa[4].z*blo(c.y) + qa[4].w*bhi(c.y);
    s += qa[5].x*blo(c.z) + qa[5].y*bhi(c.z) + qa[5].z*blo(c.w) + qa[5].w*bhi(c.w);
    s += qa[6].x*blo(d.x) + qa[6].y*bhi(d.x) + qa[6].z*blo(d.y) + qa[6].w*bhi(d.y);
    s += qa[7].x*blo(d.z) + qa[7].y*bhi(d.z) + qa[7].z*blo(d.w) + qa[7].w*bhi(d.w);
    return s;
}

// ---------------- K3: fused attention + tail. 512 threads = 8 waves x 1 node = 8-node tile ----
// grid 512 blocks -> 2 blocks/CU co-resident (46KB LDS) = 16 waves/CU
__global__ void __launch_bounds__(512) k_attn_tail(
        const float* __restrict__ qf, const unsigned short* __restrict__ kb,
        const unsigned short* __restrict__ vb, const unsigned* __restrict__ adj,
        const float* __restrict__ emb,
        const unsigned short* __restrict__ Bow, const float* __restrict__ ob,
        const unsigned short* __restrict__ Blw, const float* __restrict__ lb,
        const float* __restrict__ g, const float* __restrict__ beta,
        float* __restrict__ out){
    __shared__ float  sS[8][8][SP];      // 33.8 KB; later reused as xs[16*264]
    __shared__ int    sNbr[8][MAXD];     // 4 KB
    __shared__ short8 sPk[512];          // 8 KB fragment staging (16 rows; rows 8-15 dead)
    __shared__ float  sInv[8][8];
    __shared__ int    sDeg[8];
    int bx = blockIdx.x, t = threadIdx.x;
    int wv = t >> 6, lane = t & 63;
    int n0 = bx * 8;
    int n = n0 + wv;                     // this wave's node; row within tile = wv
    float* xs = (float*)sS;

    // ======== ATTENTION: one node per wave, no barriers ========
    // --- neighbor extraction: lane holds adj words 2*lane, 2*lane+1 ---
    uint2 aw = ((const uint2*)(adj + n * 128))[lane];
    int cnt = __popc(aw.x) + __popc(aw.y);
    int pre = cnt;
    #pragma unroll
    for (int off = 1; off < 64; off <<= 1){
        int tmp = __shfl_up(pre, off);
        if (lane >= off) pre += tmp;
    }
    int tot = __shfl(pre, 63);
    int dg = (tot < MAXD) ? tot : MAXD;
    if (lane == 63) sDeg[wv] = dg;
    int base = pre - cnt;
    int mb = lane * 64;
    unsigned b0 = aw.x, b1 = aw.y;
    while (b0){ int b = __ffs(b0) - 1; b0 &= b0 - 1u; if (base < MAXD) sNbr[wv][base] = mb + b; base++; }
    mb += 32;
    while (b1){ int b = __ffs(b1) - 1; b1 &= b1 - 1u; if (base < MAXD) sNbr[wv][base] = mb + b; base++; }

    if (dg > 0){
        asm volatile("s_waitcnt lgkmcnt(0)" ::: "memory");

        // --- scores: lane = (j-slot js = lane>>3, head h = lane&7); 2-way j unroll ---
        int js = lane >> 3, h = lane & 7;
        float4 qa[8];
        const float4* q4 = (const float4*)(qf + n * 256 + h * 32);
        #pragma unroll
        for (int i = 0; i < 8; ++i) qa[i] = q4[i];
        for (int jb = 0; jb < dg; jb += 16){
            int j0 = jb + js, j1 = jb + 8 + js;
            bool v0 = j0 < dg, v1 = j1 < dg;
            int m0 = v0 ? sNbr[wv][j0] : sNbr[wv][0];
            int m1 = v1 ? sNbr[wv][j1] : sNbr[wv][0];
            const uint4* kr0 = (const uint4*)(kb + m0 * 256) + h * 4;
            const uint4* kr1 = (const uint4*)(kb + m1 * 256) + h * 4;
            uint4 a0 = kr0[0], a1 = kr0[1], a2 = kr0[2], a3 = kr0[3];
            uint4 c0 = kr1[0], c1 = kr1[1], c2 = kr1[2], c3 = kr1[3];
            float s0 = dot32(qa, a0, a1, a2, a3) * 0.17677669529663687f;
            float s1 = dot32(qa, c0, c1, c2, c3) * 0.17677669529663687f;
            if (v0) sS[wv][h][j0] = s0;
            if (v1) sS[wv][h][j1] = s1;
        }
        asm volatile("s_waitcnt lgkmcnt(0)" ::: "memory");

        // --- softmax: lane = (h2 = lane>>3, i2 = lane&7) ---
        int h2 = lane >> 3, i2 = lane & 7;
        float m1 = -1e30f;
        for (int j = i2; j < dg; j += 8) m1 = fmaxf(m1, sS[wv][h2][j]);
        m1 = fmaxf(m1, __shfl_xor(m1, 1));
        m1 = fmaxf(m1, __shfl_xor(m1, 2));
        m1 = fmaxf(m1, __shfl_xor(m1, 4));
        float sum = 0.f;
        for (int j = i2; j < dg; j += 8){ float e = __expf(sS[wv][h2][j] - m1); sS[wv][h2][j] = e; sum += e; }
        sum += __shfl_xor(sum, 1);
        sum += __shfl_xor(sum, 2);
        sum += __shfl_xor(sum, 4);
        if (i2 == 0) sInv[wv][h2] = 1.0f / sum;
        asm volatile("s_waitcnt lgkmcnt(0)" ::: "memory");

        // --- values: lane covers dims 4*lane..4*lane+3; 8-way j unroll; 8B loads ---
        int h3 = lane >> 3;
        const uint2* vb2 = (const uint2*)vb;
        float4 O = {0.f, 0.f, 0.f, 0.f};
        int j = 0;
        for (; j + 8 <= dg; j += 8){
            uint2 uu[8]; float ww[8];
            #pragma unroll
            for (int k = 0; k < 8; ++k){
                uu[k] = vb2[sNbr[wv][j + k] * 64 + lane];
                ww[k] = sS[wv][h3][j + k];
            }
            #pragma unroll
            for (int k = 0; k < 8; ++k){
                O.x += ww[k] * blo(uu[k].x); O.y += ww[k] * bhi(uu[k].x);
                O.z += ww[k] * blo(uu[k].y); O.w += ww[k] * bhi(uu[k].y);
            }
        }
        for (; j < dg; ++j){
            uint2 u = vb2[sNbr[wv][j] * 64 + lane];
            float wgt = sS[wv][h3][j];
            O.x += wgt * blo(u.x); O.y += wgt * bhi(u.x);
            O.z += wgt * blo(u.y); O.w += wgt * bhi(u.y);
        }
        float inv = sInv[wv][h3];

        // --- pack ctx row wv into LDS A-fragments ---
        int d0 = lane * 4;
        int s  = d0 >> 5;
        int l2 = ((d0 >> 3) & 3) * 16 + wv;
        uint2 pk;
        pk.x = (unsigned)f2bf(O.x * inv) | ((unsigned)f2bf(O.y * inv) << 16);
        pk.y = (unsigned)f2bf(O.z * inv) | ((unsigned)f2bf(O.w * inv) << 16);
        ((uint2*)sPk)[(s * 64 + l2) * 2 + ((d0 & 7) >> 2)] = pk;
    }
    __syncthreads();

    // ======== TAIL: out-proj + passthrough -> pack -> lin -> LayerNorm -> GELU ========
    // 8 waves x 2 col-tiles = 256 cols; output rows 0-7 valid (A rows 8-15 garbage, contained)
    const short8* B8 = (const short8*)Bow;
    float4v acc[2];
    #pragma unroll
    for (int c = 0; c < 2; ++c) acc[c] = (float4v){0.f, 0.f, 0.f, 0.f};
    #pragma unroll
    for (int s = 0; s < 8; ++s){
        short8 a = sPk[s * 64 + lane];
        #pragma unroll
        for (int c = 0; c < 2; ++c)
            acc[c] = __builtin_amdgcn_mfma_f32_16x16x32_bf16(a, B8[((wv * 2 + c) * 8 + s) * 64 + lane], acc[c], 0, 0, 0);
    }
    int q = lane >> 4, col = lane & 15;
    #pragma unroll
    for (int c = 0; c < 2; ++c){
        int o = (wv * 2 + c) * 16 + col;
        float bo = ob[o];
        #pragma unroll
        for (int r = 0; r < 4; ++r){
            int row = q * 4 + r;                 // 0..15; only 0..7 valid
            if (row < 8){
                float x = acc[c][r] + bo;
                if (sDeg[row] == 0) x = emb[(n0 + row) * 256 + o];
                xs[row * 264 + o] = x;
            }
        }
    }
    __syncthreads();

    // pack x -> bf16 fragments (512 entries; rows 8-15 zeroed)
    {
        int l2 = t & 63, s = t >> 6;
        int mm = l2 & 15, k0 = s * 32 + ((l2 >> 4) << 3);
        short8 v;
        if (mm < 8){
            #pragma unroll
            for (int j = 0; j < 8; ++j) v[j] = (short)f2bf(xs[mm * 264 + k0 + j]);
        } else {
            #pragma unroll
            for (int j = 0; j < 8; ++j) v[j] = 0;
        }
        sPk[t] = v;      // safe: all prior sPk reads happened before previous barrier
    }
    __syncthreads();

    // lin MFMA
    const short8* B2 = (const short8*)Blw;
    float4v acc2[2];
    #pragma unroll
    for (int c = 0; c < 2; ++c) acc2[c] = (float4v){0.f, 0.f, 0.f, 0.f};
    #pragma unroll
    for (int s = 0; s < 8; ++s){
        short8 a = sPk[s * 64 + lane];
        #pragma unroll
        for (int c = 0; c < 2; ++c)
            acc2[c] = __builtin_amdgcn_mfma_f32_16x16x32_bf16(a, B2[((wv * 2 + c) * 8 + s) * 64 + lane], acc2[c], 0, 0, 0);
    }
    __syncthreads();                     // pack xs reads done; reuse xs as ys
    #pragma unroll
    for (int c = 0; c < 2; ++c){
        int o = (wv * 2 + c) * 16 + col;
        float bo = lb[o];
        #pragma unroll
        for (int r = 0; r < 4; ++r){
            int row = q * 4 + r;
            if (row < 8) xs[row * 264 + o] = acc2[c][r] + bo;
        }
    }
    __syncthreads();

    // LayerNorm + exact GELU: wave per row (rr = wv), 64 lanes x 4 cols
    int i = lane;
    float s1 = 0.f, s2 = 0.f;
    #pragma unroll
    for (int jj = 0; jj < 4; ++jj){ float v = xs[wv * 264 + i + 64 * jj]; s1 += v; s2 += v * v; }
    #pragma unroll
    for (int off = 32; off > 0; off >>= 1){ s1 += __shfl_xor(s1, off); s2 += __shfl_xor(s2, off); }
    float mu = s1 * (1.0f / 256.0f);
    float var = s2 * (1.0f / 256.0f) - mu * mu;
    float rs = rsqrtf(fmaxf(var, 0.f) + 1e-5f);
    int nbase = (n0 + wv) * 256;
    #pragma unroll
    for (int jj = 0; jj < 4; ++jj){
        int cc = i + 64 * jj;
        float z = (xs[wv * 264 + cc] - mu) * rs * g[cc] + beta[cc];
        out[nbase + cc] = 0.5f * z * (1.0f + erff(z * 0.70710678118654752f));
    }
}

extern "C" void kernel_launch(void* const* d_in, const int* in_sizes, int n_in,
                              void* d_out, int out_size, void* d_ws, size_t ws_size,
                              hipStream_t stream){
    const float* emb = (const float*)d_in[0];
    const int*   ei  = (const int*)d_in[1];
    const float* ipw = (const float*)d_in[2];
    const float* ipb = (const float*)d_in[3];
    const float* ow  = (const float*)d_in[4];
    const float* ob  = (const float*)d_in[5];
    const float* lw  = (const float*)d_in[6];
    const float* lb  = (const float*)d_in[7];
    const float* g   = (const float*)d_in[8];
    const float* bet = (const float*)d_in[9];

    char* ws = (char*)d_ws;
    unsigned*       adj  = (unsigned*)(ws);                    // 2 MiB
    unsigned short* bipw = (unsigned short*)(ws + 2113536);    // 384 KiB
    unsigned short* bow  = (unsigned short*)(ws + 2506752);    // 128 KiB
    unsigned short* blw  = (unsigned short*)(ws + 2637824);    // 128 KiB
    float*          qf   = (float*)(ws + 2768896);             // 4 MiB
    unsigned short* kb   = (unsigned short*)(ws + 6963200);    // 2 MiB
    unsigned short* vb   = (unsigned short*)(ws + 9060352);    // 2 MiB

    k_packw    <<<160, 256, 0, stream>>>(ipw, ow, lw, bipw, bow, blw, adj);
    k_gqkv     <<<dim3(256, 3), 256, 0, stream>>>(emb, bipw, ipb, qf, kb, vb, ei, adj);
    k_attn_tail<<<512, 512, 0, stream>>>(qf, kb, vb, adj, emb, bow, ob, blw, lb, g, bet, (float*)d_out);
}